// Round 1
// baseline (47.450 us; speedup 1.0000x reference)
//
#include <hip/hip_runtime.h>
#include <math.h>

#define MAX_T 2048

// ---------------- Kernel 1: score = sigmoid(feat . W + b) ----------------
// One wave (64 lanes) per (b,t) row. float4 coalesced loads.
__global__ void score_kernel(const float* __restrict__ feat,
                             const float* __restrict__ W,
                             const float* __restrict__ bias,
                             float* __restrict__ score,
                             int nrows, int D) {
  int row = blockIdx.x * 4 + (threadIdx.x >> 6);
  int lane = threadIdx.x & 63;
  if (row >= nrows) return;
  const float4* f4 = (const float4*)(feat + (size_t)row * D);
  const float4* w4 = (const float4*)W;
  float acc = 0.f;
  int n4 = D >> 2;
  for (int idx = lane; idx < n4; idx += 64) {
    float4 a = f4[idx];
    float4 w = w4[idx];
    acc += a.x * w.x + a.y * w.y + a.z * w.z + a.w * w.w;
  }
#pragma unroll
  for (int off = 32; off > 0; off >>= 1) acc += __shfl_xor(acc, off, 64);
  if (lane == 0) {
    float x = acc + bias[0];
    score[row] = 1.f / (1.f + expf(-x));
  }
}

// ---------------- Kernel 2: valley detect + segment table ----------------
// One block (256 threads) per batch element.
__global__ void seg_kernel(const float* __restrict__ score,
                           const int* __restrict__ hlens,
                           int* __restrict__ vstart,
                           int* __restrict__ vend,
                           int* __restrict__ hn_ws,
                           float* __restrict__ hn_out,
                           int T, int M) {
  int b = blockIdx.x;
  int tid = threadIdx.x;
  __shared__ float s[MAX_T];
  __shared__ unsigned char fl[MAX_T];
  __shared__ int vi[MAX_T];
  __shared__ int psum[256];

  const float* sr = score + (size_t)b * T;
  int hl = hlens[b];

  for (int t = tid; t < T; t += 256) s[t] = sr[t];
  __syncthreads();

  // valley flags: forced at t==0 and t==hl-1; natural local-max otherwise.
  for (int t = tid; t < T; t += 256) {
    bool f;
    if (t >= hl) {
      f = false;
    } else if (t == 0 || t == hl - 1) {
      f = true;
    } else {
      float c = s[t];
      f = (c >= s[t - 1]) && (c >= s[t + 1]);
    }
    fl[t] = f ? (unsigned char)1 : (unsigned char)0;
  }
  __syncthreads();

  // blocked exclusive scan over 256 chunks of size C
  int C = (T + 255) / 256;
  int lo = tid * C;
  int hi = lo + C; if (hi > T) hi = T; if (lo > T) lo = T;
  int cnt = 0;
  for (int t = lo; t < hi; ++t) cnt += fl[t];
  psum[tid] = cnt;
  __syncthreads();
  for (int off = 1; off < 256; off <<= 1) {
    int v = (tid >= off) ? psum[tid - off] : 0;
    __syncthreads();
    psum[tid] += v;
    __syncthreads();
  }
  int excl = psum[tid] - cnt;
  int hn = psum[255];
  for (int t = lo; t < hi; ++t) {
    if (fl[t]) vi[excl++] = t;
  }
  __syncthreads();

  // segment k covers [vi[k-1], vi[k+1]) with vi[-1]:=0, last end = hl-1
  for (int k = tid; k < M; k += 256) {
    int vs = 0, ve = 0;
    if (k < hn) {
      vs = (k == 0) ? 0 : vi[k - 1];
      ve = (k == hn - 1) ? (hl - 1) : vi[k + 1];
    }
    vstart[(size_t)b * M + k] = vs;
    vend[(size_t)b * M + k] = ve;
  }
  if (tid == 0) {
    hn_ws[b] = hn;
    hn_out[b] = (float)hn;
  }
}

// ---------------- Kernel 3: segment-weighted pooling ----------------
// One block (256 threads) per (b,k) output row.
__global__ void pool_kernel(const float* __restrict__ feat,
                            const float* __restrict__ score,
                            const int* __restrict__ vstart,
                            const int* __restrict__ vend,
                            const int* __restrict__ hn_ws,
                            float* __restrict__ out,
                            int T, int D, int M) {
  int b = blockIdx.x / M;
  int k = blockIdx.x - b * M;
  int tid = threadIdx.x;
  float* o = out + ((size_t)b * M + k) * D;
  int hn = hn_ws[b];
  if (k >= hn) {
    for (int d = tid; d < D; d += 256) o[d] = 0.f;
    return;
  }
  int vs = vstart[(size_t)b * M + k];
  int ve = vend[(size_t)b * M + k];
  const float* sr = score + (size_t)b * T;
  const float* fr = feat + (size_t)b * T * (size_t)D;

  for (int d0 = 0; d0 < D; d0 += 256) {
    int d = d0 + tid;
    if (d >= D) break;
    float a = 0.f, ss = 0.f;
    for (int t = vs; t < ve; ++t) {
      float sc = sr[t];
      a += sc * fr[(size_t)t * D + d];
      ss += sc;
    }
    o[d] = a / (ss + 1e-10f);
  }
}

extern "C" void kernel_launch(void* const* d_in, const int* in_sizes, int n_in,
                              void* d_out, int out_size, void* d_ws, size_t ws_size,
                              hipStream_t stream) {
  const float* feat = (const float*)d_in[0];
  const float* W    = (const float*)d_in[1];
  const float* bias = (const float*)d_in[2];
  const int* hlens  = (const int*)d_in[3];

  int D = in_sizes[1];                 // 512
  int B = in_sizes[3];                 // 16
  int T = in_sizes[0] / (B * D);       // 2000
  int M = (out_size - B - B * T) / (B * D);  // data-dependent max segments

  float* out      = (float*)d_out;
  float* feat_new = out;                          // [B, M, D]
  float* hn_out   = out + (size_t)B * M * D;      // [B] (as float)
  float* score    = hn_out + B;                   // [B, T]

  int* hn_ws  = (int*)d_ws;          // [B]
  int* vstart = hn_ws + B;           // [B*M]
  int* vend   = vstart + B * M;      // [B*M]

  int nrows = B * T;
  score_kernel<<<(nrows + 3) / 4, 256, 0, stream>>>(feat, W, bias, score, nrows, D);
  seg_kernel<<<B, 256, 0, stream>>>(score, hlens, vstart, vend, hn_ws, hn_out, T, M);
  pool_kernel<<<B * M, 256, 0, stream>>>(feat, score, vstart, vend, hn_ws, out, T, D, M);
}

// Round 2
// 41.737 us; speedup vs baseline: 1.1369x; 1.1369x over previous
//
#include <hip/hip_runtime.h>
#include <math.h>

#define MAX_T 2048

// ---------------- Kernel 1: score = sigmoid(feat . W + b) ----------------
// One wave (64 lanes) per (b,t) row. float4 coalesced loads.
__global__ void score_kernel(const float* __restrict__ feat,
                             const float* __restrict__ W,
                             const float* __restrict__ bias,
                             float* __restrict__ score,
                             int nrows, int D) {
  int row = blockIdx.x * 4 + (threadIdx.x >> 6);
  int lane = threadIdx.x & 63;
  if (row >= nrows) return;
  const float4* f4 = (const float4*)(feat + (size_t)row * D);
  const float4* w4 = (const float4*)W;
  float acc = 0.f;
  int n4 = D >> 2;
  for (int idx = lane; idx < n4; idx += 64) {
    float4 a = f4[idx];
    float4 w = w4[idx];
    acc += a.x * w.x + a.y * w.y + a.z * w.z + a.w * w.w;
  }
#pragma unroll
  for (int off = 32; off > 0; off >>= 1) acc += __shfl_xor(acc, off, 64);
  if (lane == 0) {
    float x = acc + bias[0];
    score[row] = 1.f / (1.f + expf(-x));
  }
}

// ---------------- Kernel 2: valley detect + atom table ----------------
// One block (256 threads) per batch element. Atom j = [vi[j-1], vi[j]),
// vi[-1] := 0. Note vi[0] == 0 (forced valley at t=0) so atom 0 is empty.
// Segment k = atom k U atom k+1 (k < hn-1); segment hn-1 = atom hn-1.
__global__ void seg_kernel(const float* __restrict__ score,
                           const int* __restrict__ hlens,
                           int* __restrict__ astart,
                           int* __restrict__ aend,
                           int* __restrict__ hn_ws,
                           float* __restrict__ hn_out,
                           int T, int M) {
  int b = blockIdx.x;
  int tid = threadIdx.x;
  __shared__ float s[MAX_T];
  __shared__ unsigned char fl[MAX_T];
  __shared__ int vi[MAX_T];
  __shared__ int wsum[4];

  const float* sr = score + (size_t)b * T;
  int hl = hlens[b];

  for (int t = tid; t < T; t += 256) s[t] = sr[t];
  __syncthreads();

  // valley flags: forced at t==0 and t==hl-1; natural local-max otherwise.
  for (int t = tid; t < T; t += 256) {
    bool f;
    if (t >= hl) {
      f = false;
    } else if (t == 0 || t == hl - 1) {
      f = true;
    } else {
      float c = s[t];
      f = (c >= s[t - 1]) && (c >= s[t + 1]);
    }
    fl[t] = f ? (unsigned char)1 : (unsigned char)0;
  }
  __syncthreads();

  // blocked scan: per-thread chunk count -> wave shfl scan -> 4-wave combine
  int C = (T + 255) / 256;
  int lo = tid * C;
  int hi = lo + C; if (hi > T) hi = T; if (lo > T) lo = T;
  int cnt = 0;
  for (int t = lo; t < hi; ++t) cnt += fl[t];

  int lane = tid & 63, wid = tid >> 6;
  int incl = cnt;
#pragma unroll
  for (int off = 1; off < 64; off <<= 1) {
    int v = __shfl_up(incl, off, 64);
    if (lane >= off) incl += v;
  }
  if (lane == 63) wsum[wid] = incl;
  __syncthreads();
  int wofs = 0;
#pragma unroll
  for (int w = 0; w < 4; ++w) wofs += (w < wid) ? wsum[w] : 0;
  int hn = wsum[0] + wsum[1] + wsum[2] + wsum[3];
  int excl = wofs + incl - cnt;
  for (int t = lo; t < hi; ++t) {
    if (fl[t]) vi[excl++] = t;
  }
  __syncthreads();

  for (int j = tid; j < M; j += 256) {
    int as = 0, ae = 0;
    if (j < hn) {
      as = (j == 0) ? 0 : vi[j - 1];
      ae = vi[j];                 // vi[hn-1] == hl-1 (forced valley)
    }
    astart[(size_t)b * M + j] = as;
    aend[(size_t)b * M + j] = ae;
  }
  if (tid == 0) {
    hn_ws[b] = hn;
    hn_out[b] = (float)hn;
  }
}

// ---------------- Kernel 3: atom partial sums ----------------
// 2 atoms per block; 128 lanes (float4) per atom. Reads feat exactly once.
__global__ void atom_kernel(const float* __restrict__ feat,
                            const float* __restrict__ score,
                            const int* __restrict__ astart,
                            const int* __restrict__ aend,
                            const int* __restrict__ hn_ws,
                            float* __restrict__ asum,
                            float* __restrict__ assum,
                            int T, int D, int M) {
  int ja = blockIdx.x * 2 + (threadIdx.x >> 7);
  int lane = threadIdx.x & 127;
  int b = ja / M;
  int j = ja - b * M;
  if (b >= gridDim.x * 2 / 1) { } // no-op
  int hn = hn_ws[b];
  if (j >= hn) return;  // never read downstream
  int as = astart[(size_t)b * M + j];
  int ae = aend[(size_t)b * M + j];
  const float* sr = score + (size_t)b * T;
  const float4* fr = (const float4*)(feat + (size_t)b * T * (size_t)D);
  int n4 = D >> 2;  // 128
  float4 a = make_float4(0.f, 0.f, 0.f, 0.f);
  float ss = 0.f;
  for (int t = as; t < ae; ++t) {
    float sc = sr[t];
    float4 f = fr[(size_t)t * n4 + lane];
    a.x += sc * f.x; a.y += sc * f.y; a.z += sc * f.z; a.w += sc * f.w;
    ss += sc;
  }
  float4* o4 = (float4*)(asum + (size_t)ja * D);
  o4[lane] = a;
  if (lane == 0) assum[ja] = ss;
}

// ---------------- Kernel 4: combine adjacent atoms -> output ----------------
__global__ void combine_kernel(const float* __restrict__ asum,
                               const float* __restrict__ assum,
                               const int* __restrict__ hn_ws,
                               float* __restrict__ out,
                               int D, int M) {
  int rk = blockIdx.x * 2 + (threadIdx.x >> 7);
  int lane = threadIdx.x & 127;
  int b = rk / M;
  int k = rk - b * M;
  int n4 = D >> 2;
  float4* o4 = (float4*)(out + (size_t)rk * D);
  int hn = hn_ws[b];
  if (k >= hn) {
    o4[lane] = make_float4(0.f, 0.f, 0.f, 0.f);
    return;
  }
  const float4* a4 = (const float4*)(asum + (size_t)rk * D);
  float4 num = a4[lane];
  float den = assum[rk];
  if (k < hn - 1) {
    float4 nb = a4[lane + n4];  // asum[rk+1]
    num.x += nb.x; num.y += nb.y; num.z += nb.z; num.w += nb.w;
    den += assum[rk + 1];
  }
  float inv = 1.f / (den + 1e-10f);
  num.x *= inv; num.y *= inv; num.z *= inv; num.w *= inv;
  o4[lane] = num;
}

// ---------------- Fallback: direct pool (if ws too small) ----------------
__global__ void pool_kernel(const float* __restrict__ feat,
                            const float* __restrict__ score,
                            const int* __restrict__ astart,
                            const int* __restrict__ aend,
                            const int* __restrict__ hn_ws,
                            float* __restrict__ out,
                            int T, int D, int M) {
  int b = blockIdx.x / M;
  int k = blockIdx.x - b * M;
  int tid = threadIdx.x;
  float* o = out + ((size_t)b * M + k) * D;
  int hn = hn_ws[b];
  if (k >= hn) {
    for (int d = tid; d < D; d += 256) o[d] = 0.f;
    return;
  }
  int vs = astart[(size_t)b * M + k];
  int ve = aend[(size_t)b * M + k + ((k < hn - 1) ? 1 : 0)];
  const float* sr = score + (size_t)b * T;
  const float* fr = feat + (size_t)b * T * (size_t)D;
  for (int d0 = 0; d0 < D; d0 += 256) {
    int d = d0 + tid;
    if (d >= D) break;
    float a = 0.f, ss = 0.f;
    for (int t = vs; t < ve; ++t) {
      float sc = sr[t];
      a += sc * fr[(size_t)t * D + d];
      ss += sc;
    }
    o[d] = a / (ss + 1e-10f);
  }
}

extern "C" void kernel_launch(void* const* d_in, const int* in_sizes, int n_in,
                              void* d_out, int out_size, void* d_ws, size_t ws_size,
                              hipStream_t stream) {
  const float* feat = (const float*)d_in[0];
  const float* W    = (const float*)d_in[1];
  const float* bias = (const float*)d_in[2];
  const int* hlens  = (const int*)d_in[3];

  int D = in_sizes[1];                 // 512
  int B = in_sizes[3];                 // 16
  int T = in_sizes[0] / (B * D);       // 2000
  int M = (out_size - B - B * T) / (B * D);  // data-dependent max segments

  float* out      = (float*)d_out;
  float* hn_out   = out + (size_t)B * M * D;      // [B] (as float)
  float* score    = hn_out + B;                   // [B, T]

  // ws layout: asum[B*M*D] f32 | assum[B*M] f32 | astart[B*M] | aend[B*M] | hn_ws[B]
  size_t nBM = (size_t)B * M;
  float* asum  = (float*)d_ws;
  float* assum = asum + nBM * D;
  int* astart  = (int*)(assum + nBM);
  int* aend    = astart + nBM;
  int* hn_ws   = aend + nBM;
  size_t needed = (nBM * D + nBM * 3 + B) * sizeof(float);

  int nrows = B * T;
  score_kernel<<<(nrows + 3) / 4, 256, 0, stream>>>(feat, W, bias, score, nrows, D);

  if (needed <= ws_size) {
    seg_kernel<<<B, 256, 0, stream>>>(score, hlens, astart, aend, hn_ws, hn_out, T, M);
    int nAtomBlocks = (int)((nBM + 1) / 2);
    atom_kernel<<<nAtomBlocks, 256, 0, stream>>>(feat, score, astart, aend, hn_ws,
                                                 asum, assum, T, D, M);
    combine_kernel<<<nAtomBlocks, 256, 0, stream>>>(asum, assum, hn_ws, out, D, M);
  } else {
    // minimal-ws fallback
    int* f_hn     = (int*)d_ws;
    int* f_astart = f_hn + B;
    int* f_aend   = f_astart + nBM;
    seg_kernel<<<B, 256, 0, stream>>>(score, hlens, f_astart, f_aend, f_hn, hn_out, T, M);
    pool_kernel<<<(int)nBM, 256, 0, stream>>>(feat, score, f_astart, f_aend, f_hn,
                                              out, T, D, M);
  }
}

// Round 3
// 39.060 us; speedup vs baseline: 1.2148x; 1.0685x over previous
//
#include <hip/hip_runtime.h>
#include <math.h>

#define MAX_T 2048
#define SEG_P 8   // segments per 128-lane group in the pool kernel

// ---------------- Kernel 1: score = sigmoid(feat . W + b) ----------------
// One wave (64 lanes) per (b,t) row. float4 coalesced loads.
__global__ void score_kernel(const float* __restrict__ feat,
                             const float* __restrict__ W,
                             const float* __restrict__ bias,
                             float* __restrict__ score,
                             int nrows, int D) {
  int row = blockIdx.x * 4 + (threadIdx.x >> 6);
  int lane = threadIdx.x & 63;
  if (row >= nrows) return;
  const float4* f4 = (const float4*)(feat + (size_t)row * D);
  const float4* w4 = (const float4*)W;
  float acc = 0.f;
  int n4 = D >> 2;
  for (int idx = lane; idx < n4; idx += 64) {
    float4 a = f4[idx];
    float4 w = w4[idx];
    acc += a.x * w.x + a.y * w.y + a.z * w.z + a.w * w.w;
  }
#pragma unroll
  for (int off = 32; off > 0; off >>= 1) acc += __shfl_xor(acc, off, 64);
  if (lane == 0) {
    float x = acc + bias[0];
    score[row] = 1.f / (1.f + expf(-x));
  }
}

// ---------------- Kernel 2: valley detect -> vi table ----------------
// One block (256 threads) per batch element. vi[j] = frame index of valley j.
// Atom j := [vi[j-1], vi[j]) with vi[-1]:=0 (atom 0 empty since vi[0]==0).
// Segment k = atom k U atom k+1 (k<hn-1); segment hn-1 = atom hn-1
// (because vi[hn-1] == hl-1 is the forced last valley).
__global__ void seg_kernel(const float* __restrict__ score,
                           const int* __restrict__ hlens,
                           int* __restrict__ vi_ws,
                           int* __restrict__ hn_ws,
                           float* __restrict__ hn_out,
                           int T, int M) {
  int b = blockIdx.x;
  int tid = threadIdx.x;
  __shared__ float s[MAX_T];
  __shared__ unsigned char fl[MAX_T];
  __shared__ int vi[MAX_T];
  __shared__ int wsum[4];

  const float* sr = score + (size_t)b * T;
  int hl = hlens[b];

  for (int t = tid; t < T; t += 256) s[t] = sr[t];
  __syncthreads();

  for (int t = tid; t < T; t += 256) {
    bool f;
    if (t >= hl) {
      f = false;
    } else if (t == 0 || t == hl - 1) {
      f = true;
    } else {
      float c = s[t];
      f = (c >= s[t - 1]) && (c >= s[t + 1]);
    }
    fl[t] = f ? (unsigned char)1 : (unsigned char)0;
  }
  __syncthreads();

  // blocked scan: per-thread chunk count -> wave shfl scan -> 4-wave combine
  int C = (T + 255) / 256;
  int lo = tid * C;
  int hi = lo + C; if (hi > T) hi = T; if (lo > T) lo = T;
  int cnt = 0;
  for (int t = lo; t < hi; ++t) cnt += fl[t];

  int lane = tid & 63, wid = tid >> 6;
  int incl = cnt;
#pragma unroll
  for (int off = 1; off < 64; off <<= 1) {
    int v = __shfl_up(incl, off, 64);
    if (lane >= off) incl += v;
  }
  if (lane == 63) wsum[wid] = incl;
  __syncthreads();
  int wofs = 0;
#pragma unroll
  for (int w = 0; w < 4; ++w) wofs += (w < wid) ? wsum[w] : 0;
  int hn = wsum[0] + wsum[1] + wsum[2] + wsum[3];
  int excl = wofs + incl - cnt;
  for (int t = lo; t < hi; ++t) {
    if (fl[t]) vi[excl++] = t;
  }
  __syncthreads();

  for (int j = tid; j < M; j += 256) {
    vi_ws[(size_t)b * M + j] = (j < hn) ? vi[j] : 0;
  }
  if (tid == 0) {
    hn_ws[b] = hn;
    hn_out[b] = (float)hn;
  }
}

// ---------------- Kernel 3: grouped rolling-atom pool ----------------
// Each 128-lane group owns SEG_P consecutive segments of one batch.
// It computes atom sums k0..k0+SEG_P with a 2-deep rolling register window
// and emits out[k] = (atom_k + atom_{k+1}) / (ss_k + ss_{k+1} + 1e-10).
// feat is read (P+1)/P times total; no intermediate buffers.
__global__ void pool_kernel(const float* __restrict__ feat,
                            const float* __restrict__ score,
                            const int* __restrict__ vi_ws,
                            const int* __restrict__ hn_ws,
                            float* __restrict__ out,
                            int T, int D, int M, int ngrp) {
  int gid = blockIdx.x * 2 + (threadIdx.x >> 7);
  int lane = threadIdx.x & 127;          // 128 lanes, float4 over D=512
  int b = gid / ngrp;
  int g = gid - b * ngrp;
  int k0 = g * SEG_P;
  if (k0 >= M) return;

  int hn = hn_ws[b];
  const int* vi = vi_ws + (size_t)b * M;
  const float* sr = score + (size_t)b * T;
  const float4* fr = (const float4*)(feat + (size_t)b * T * (size_t)D);
  int n4 = D >> 2;                       // 128

  int kend = k0 + SEG_P; if (kend > M) kend = M;

  // rolling atom accumulators
  float4 ap = make_float4(0.f, 0.f, 0.f, 0.f);
  float ssp = 0.f;
  if (k0 < hn) {
    int as = (k0 == 0) ? 0 : vi[k0 - 1];
    int ae = vi[k0];
    for (int t = as; t < ae; ++t) {
      float sc = sr[t];
      float4 f = fr[(size_t)t * n4 + lane];
      ap.x += sc * f.x; ap.y += sc * f.y; ap.z += sc * f.z; ap.w += sc * f.w;
      ssp += sc;
    }
  }

  for (int k = k0; k < kend; ++k) {
    float4* o4 = (float4*)(out + ((size_t)b * M + k) * D);
    if (k >= hn) {
      o4[lane] = make_float4(0.f, 0.f, 0.f, 0.f);
      continue;
    }
    if (k == hn - 1) {
      float inv = 1.f / (ssp + 1e-10f);
      o4[lane] = make_float4(ap.x * inv, ap.y * inv, ap.z * inv, ap.w * inv);
      ssp = 0.f; ap = make_float4(0.f, 0.f, 0.f, 0.f);
      continue;
    }
    // atom k+1
    float4 ac = make_float4(0.f, 0.f, 0.f, 0.f);
    float ssc = 0.f;
    {
      int as = vi[k];
      int ae = vi[k + 1];
      for (int t = as; t < ae; ++t) {
        float sc = sr[t];
        float4 f = fr[(size_t)t * n4 + lane];
        ac.x += sc * f.x; ac.y += sc * f.y; ac.z += sc * f.z; ac.w += sc * f.w;
        ssc += sc;
      }
    }
    float inv = 1.f / (ssp + ssc + 1e-10f);
    o4[lane] = make_float4((ap.x + ac.x) * inv, (ap.y + ac.y) * inv,
                           (ap.z + ac.z) * inv, (ap.w + ac.w) * inv);
    ap = ac; ssp = ssc;
  }
}

extern "C" void kernel_launch(void* const* d_in, const int* in_sizes, int n_in,
                              void* d_out, int out_size, void* d_ws, size_t ws_size,
                              hipStream_t stream) {
  const float* feat = (const float*)d_in[0];
  const float* W    = (const float*)d_in[1];
  const float* bias = (const float*)d_in[2];
  const int* hlens  = (const int*)d_in[3];

  int D = in_sizes[1];                 // 512
  int B = in_sizes[3];                 // 16
  int T = in_sizes[0] / (B * D);       // 2000
  int M = (out_size - B - B * T) / (B * D);  // data-dependent max segments

  float* out      = (float*)d_out;
  float* hn_out   = out + (size_t)B * M * D;      // [B] (as float)
  float* score    = hn_out + B;                   // [B, T]

  // ws layout: vi[B*M] int | hn_ws[B] int
  int* vi_ws = (int*)d_ws;
  int* hn_ws = vi_ws + (size_t)B * M;

  int nrows = B * T;
  score_kernel<<<(nrows + 3) / 4, 256, 0, stream>>>(feat, W, bias, score, nrows, D);
  seg_kernel<<<B, 256, 0, stream>>>(score, hlens, vi_ws, hn_ws, hn_out, T, M);

  int ngrp = (M + SEG_P - 1) / SEG_P;
  int ngroups = B * ngrp;
  pool_kernel<<<(ngroups + 1) / 2, 256, 0, stream>>>(feat, score, vi_ws, hn_ws,
                                                     out, T, D, M, ngrp);
}